// Round 1
// baseline (865.949 us; speedup 1.0000x reference)
//
#include <hip/hip_runtime.h>

// AttnHGCN.forward_ui — 3-layer bipartite LightGCN-style propagation.
// R6: (a) non-temporal (nt) loads on all STREAMING reads: edge quads in
//     hist/scatter, csr entries in gather. Theory: R5's XCD-pinned 4MB CSR
//     windows match L2 size, but the 48MB/pass edge stream through the same
//     L2 evicts dirty partially-filled CSR lines -> 236MB WRITE_SIZE for a
//     32MB payload. nt marks the stream evict-first so dirty lines survive
//     until full. Stores stay temporal (CSR lines MUST allocate in L2).
//     (b) gather adjacency loop unrolled x4 (16 row-gathers in flight per
//     wave): gathers ran at ~5.6TB/s over L3-resident data = latency-bound.

constexpr int N_USERS = 100000;
constexpr int N_ITEMS = 50000;
constexpr int CH      = 64;
constexpr int N_EDGES = 2000000;
constexpr int LAYERS  = 3;
constexpr int NROWS   = N_USERS + N_ITEMS;          // 150000 combined dest rows
constexpr int NDIR    = 2 * N_EDGES;                // 4M directed edges

constexpr int PASSES  = 8;
constexpr int WROWS   = NROWS / PASSES;             // 18750 rows per window
constexpr int QEDGES  = N_EDGES / 4;                // 500000 int4 edge-quads
constexpr int BPP     = (QEDGES + 255) / 256;       // blocks per pass = 1954

constexpr long long ITEM_ELEMS = (long long)N_ITEMS * CH;  // 3,200,000
constexpr long long USER_ELEMS = (long long)N_USERS * CH;  // 6,400,000
constexpr long long TOT_ELEMS  = ITEM_ELEMS + USER_ELEMS;  // 9,600,000

// ext-vector types so __builtin_nontemporal_load works (HIP int4 is a struct)
typedef int   v4i __attribute__((ext_vector_type(4)));
typedef int   v2i __attribute__((ext_vector_type(2)));
typedef float v4f __attribute__((ext_vector_type(4)));

static __device__ __forceinline__ v4i nt_load4i(const void* p) {
  return __builtin_nontemporal_load((const v4i*)p);
}
static __device__ __forceinline__ v4f nt_load4f(const void* p) {
  return __builtin_nontemporal_load((const v4f*)p);
}
static __device__ __forceinline__ v2i nt_load2i(const void* p) {
  return __builtin_nontemporal_load((const v2i*)p);
}

// ---------------- CSR build ----------------

__global__ __launch_bounds__(256) void hist_kernel(
    const int* __restrict__ u_idx, const int* __restrict__ i_idx,
    int* __restrict__ counts) {
  int q = blockIdx.x * 256 + threadIdx.x;
  if (q >= QEDGES) return;
  v4i u  = nt_load4i(u_idx + 4 * (long long)q);
  v4i it = nt_load4i(i_idx + 4 * (long long)q);
  atomicAdd(&counts[u.x], 1);
  atomicAdd(&counts[u.y], 1);
  atomicAdd(&counts[u.z], 1);
  atomicAdd(&counts[u.w], 1);
  atomicAdd(&counts[N_USERS + it.x], 1);
  atomicAdd(&counts[N_USERS + it.y], 1);
  atomicAdd(&counts[N_USERS + it.z], 1);
  atomicAdd(&counts[N_USERS + it.w], 1);
}

// per-256-block exclusive scan; block sums out
__global__ __launch_bounds__(256) void scanA_kernel(
    const int* __restrict__ counts, int* __restrict__ row_ptr,
    int* __restrict__ blksums, int n) {
  __shared__ int sh[256];
  int t = threadIdx.x;
  int i = blockIdx.x * 256 + t;
  int v = (i < n) ? counts[i] : 0;
  int x = v;
  sh[t] = x; __syncthreads();
  for (int d = 1; d < 256; d <<= 1) {
    int add = (t >= d) ? sh[t - d] : 0;
    __syncthreads();
    x += add; sh[t] = x;
    __syncthreads();
  }
  if (i < n) row_ptr[i] = x - v;  // exclusive within block
  if (t == 255) blksums[blockIdx.x] = x;
}

// single-block exclusive scan of block sums (n2 <= 1024)
__global__ __launch_bounds__(1024) void scanB_kernel(int* __restrict__ blksums, int n2) {
  __shared__ int sh[1024];
  int t = threadIdx.x;
  int v = (t < n2) ? blksums[t] : 0;
  int x = v;
  sh[t] = x; __syncthreads();
  for (int d = 1; d < 1024; d <<= 1) {
    int add = (t >= d) ? sh[t - d] : 0;
    __syncthreads();
    x += add; sh[t] = x;
    __syncthreads();
  }
  if (t < n2) blksums[t] = x - v;  // exclusive
}

// add block offsets; init cursor; set terminator
__global__ __launch_bounds__(256) void scanC_kernel(
    int* __restrict__ row_ptr, const int* __restrict__ blksums,
    int* __restrict__ cursor, int n) {
  int i = blockIdx.x * 256 + threadIdx.x;
  if (i < n) {
    int p = row_ptr[i] + blksums[i >> 8];
    row_ptr[i] = p;
    cursor[i] = p;
  }
  if (i == 0) row_ptr[n] = NDIR;
}

// XCD-pinned windowed scatter. pass = blockIdx % PASSES so (round-robin
// blockIdx->XCD heuristic) window w's ~4MB of slots is written only by
// XCD w. Edge reads are nt (evict-first) so the 48MB/pass stream does not
// evict the dirty partial CSR lines from that 4MB L2.
__global__ __launch_bounds__(256) void scatter_csr_win(
    const int* __restrict__ u_idx, const int* __restrict__ i_idx,
    const float* __restrict__ wv, int* __restrict__ cursor,
    int2* __restrict__ csr) {
  int pass = blockIdx.x % PASSES;
  int q = (blockIdx.x / PASSES) * 256 + threadIdx.x;
  if (q >= QEDGES) return;
  const int wlo = pass * WROWS;

  v4i u  = nt_load4i(u_idx + 4 * (long long)q);
  v4i it = nt_load4i(i_idx + 4 * (long long)q);
  v4f w  = nt_load4f(wv + 4 * (long long)q);

#define PROC(UU, II, WW)                                             \
  {                                                                  \
    int ru = (UU), ri = N_USERS + (II);                              \
    int wb = __float_as_int(WW);                                     \
    if ((unsigned)(ru - wlo) < (unsigned)WROWS) {                    \
      int p = atomicAdd(&cursor[ru], 1);                             \
      csr[p] = make_int2((II), wb);                                  \
    }                                                                \
    if ((unsigned)(ri - wlo) < (unsigned)WROWS) {                    \
      int p = atomicAdd(&cursor[ri], 1);                             \
      csr[p] = make_int2((UU), wb);                                  \
    }                                                                \
  }
  PROC(u.x, it.x, w.x)
  PROC(u.y, it.y, w.y)
  PROC(u.z, it.z, w.z)
  PROC(u.w, it.w, w.w)
#undef PROC
}

// ---------------- per-layer fused gather ----------------
// One wave per destination row; lane = slot(2b) x chan16(4b); adjacency loop
// unrolled x4 -> 16 edges (16x256B gathers) in flight per wave; butterfly-
// reduce slots. csr-entry reads are nt (32MB/layer stream; keep L2 for the
// gather tables). Epilogue fuses residual accumulation:
//   MODE 0 (layer 1):   dst = acc;  out = emb + acc
//   MODE 1 (mid layer): dst = acc;  out += acc
//   MODE 2 (last):                  out = (out + acc) * 1/(LAYERS+1)
template <int MODE>
__global__ __launch_bounds__(256) void gather_fused(
    const float* __restrict__ it_tab,  // gather-source item table
    const float* __restrict__ u_tab,   // gather-source user table
    float* __restrict__ dst,           // [it|u] layer output (MODE<2)
    float* __restrict__ out,           // [item_acc | user_acc]
    const int2* __restrict__ csr,
    const int* __restrict__ row_ptr) {
  int row = blockIdx.x * 4 + (threadIdx.x >> 6);
  if (row >= NROWS) return;
  int lane = threadIdx.x & 63;
  int slot = lane >> 4;          // 0..3
  int c4   = (lane & 15) * 4;    // channel offset 0..60

  const float* gtab;             // opposite-side table to gather from
  const float* erow = nullptr;   // dest-side input-emb row (MODE 0)
  float* drow = nullptr;
  float* orow;
  if (row < N_USERS) {
    gtab = it_tab;
    orow = out + ITEM_ELEMS + (long long)row * CH;
    if (MODE < 2)  drow = dst + ITEM_ELEMS + (long long)row * CH;
    if (MODE == 0) erow = u_tab + (long long)row * CH;  // u_tab==user_emb here
  } else {
    int r = row - N_USERS;
    gtab = u_tab;
    orow = out + (long long)r * CH;
    if (MODE < 2)  drow = dst + (long long)r * CH;
    if (MODE == 0) erow = it_tab + (long long)r * CH;   // it_tab==item_emb here
  }

  int beg = row_ptr[row], end = row_ptr[row + 1];
  float4 acc = make_float4(0.f, 0.f, 0.f, 0.f);
  int j = beg + slot;
  // unrolled x4: four independent (csr, row) load pairs in flight per slot
  for (; j + 12 < end; j += 16) {
    v2i e0 = nt_load2i(csr + j);
    v2i e1 = nt_load2i(csr + j + 4);
    v2i e2 = nt_load2i(csr + j + 8);
    v2i e3 = nt_load2i(csr + j + 12);
    float4 v0 = *(const float4*)(gtab + (long long)e0.x * CH + c4);
    float4 v1 = *(const float4*)(gtab + (long long)e1.x * CH + c4);
    float4 v2 = *(const float4*)(gtab + (long long)e2.x * CH + c4);
    float4 v3 = *(const float4*)(gtab + (long long)e3.x * CH + c4);
    float w0 = __int_as_float(e0.y);
    float w1 = __int_as_float(e1.y);
    float w2 = __int_as_float(e2.y);
    float w3 = __int_as_float(e3.y);
    acc.x += w0 * v0.x; acc.y += w0 * v0.y;
    acc.z += w0 * v0.z; acc.w += w0 * v0.w;
    acc.x += w1 * v1.x; acc.y += w1 * v1.y;
    acc.z += w1 * v1.z; acc.w += w1 * v1.w;
    acc.x += w2 * v2.x; acc.y += w2 * v2.y;
    acc.z += w2 * v2.z; acc.w += w2 * v2.w;
    acc.x += w3 * v3.x; acc.y += w3 * v3.y;
    acc.z += w3 * v3.z; acc.w += w3 * v3.w;
  }
  // x2 step
  if (j + 4 < end) {
    v2i e0 = nt_load2i(csr + j);
    v2i e1 = nt_load2i(csr + j + 4);
    float4 v0 = *(const float4*)(gtab + (long long)e0.x * CH + c4);
    float4 v1 = *(const float4*)(gtab + (long long)e1.x * CH + c4);
    float w0 = __int_as_float(e0.y);
    float w1 = __int_as_float(e1.y);
    acc.x += w0 * v0.x; acc.y += w0 * v0.y;
    acc.z += w0 * v0.z; acc.w += w0 * v0.w;
    acc.x += w1 * v1.x; acc.y += w1 * v1.y;
    acc.z += w1 * v1.z; acc.w += w1 * v1.w;
    j += 8;
  }
  if (j < end) {
    v2i e = nt_load2i(csr + j);
    float we = __int_as_float(e.y);
    float4 v = *(const float4*)(gtab + (long long)e.x * CH + c4);
    acc.x += we * v.x; acc.y += we * v.y;
    acc.z += we * v.z; acc.w += we * v.w;
  }
  for (int off = 16; off < 64; off <<= 1) {
    acc.x += __shfl_xor(acc.x, off, 64);
    acc.y += __shfl_xor(acc.y, off, 64);
    acc.z += __shfl_xor(acc.z, off, 64);
    acc.w += __shfl_xor(acc.w, off, 64);
  }
  if (slot == 0) {
    if (MODE == 0) {
      float4 e4 = *(const float4*)(erow + c4);
      *(float4*)(drow + c4) = acc;
      e4.x += acc.x; e4.y += acc.y; e4.z += acc.z; e4.w += acc.w;
      *(float4*)(orow + c4) = e4;
    } else if (MODE == 1) {
      float4 o = *(const float4*)(orow + c4);
      *(float4*)(drow + c4) = acc;
      o.x += acc.x; o.y += acc.y; o.z += acc.z; o.w += acc.w;
      *(float4*)(orow + c4) = o;
    } else {
      const float s = 1.0f / (LAYERS + 1);
      float4 o = *(const float4*)(orow + c4);
      o.x = (o.x + acc.x) * s; o.y = (o.y + acc.y) * s;
      o.z = (o.z + acc.z) * s; o.w = (o.w + acc.w) * s;
      *(float4*)(orow + c4) = o;
    }
  }
}

// ---------------- fallback (R1 atomic path) ----------------

__global__ __launch_bounds__(256) void atomic_scatter_kernel(
    const float* __restrict__ src, float* __restrict__ dst,
    const int* __restrict__ u_idx, const int* __restrict__ i_idx,
    const float* __restrict__ w) {
  long long tid = (long long)blockIdx.x * blockDim.x + threadIdx.x;
  int edge = (int)(tid >> 4);
  if (edge >= N_EDGES) return;
  int c = ((int)tid & 15) * 4;
  int ui = u_idx[edge], ii = i_idx[edge];
  float we = w[edge];
  float4 itv = *(const float4*)(src + (long long)ii * CH + c);
  float4 uv  = *(const float4*)(src + ITEM_ELEMS + (long long)ui * CH + c);
  float* ud = dst + ITEM_ELEMS + (long long)ui * CH + c;
  float* id = dst + (long long)ii * CH + c;
  unsafeAtomicAdd(ud + 0, we * itv.x);
  unsafeAtomicAdd(ud + 1, we * itv.y);
  unsafeAtomicAdd(ud + 2, we * itv.z);
  unsafeAtomicAdd(ud + 3, we * itv.w);
  unsafeAtomicAdd(id + 0, we * uv.x);
  unsafeAtomicAdd(id + 1, we * uv.y);
  unsafeAtomicAdd(id + 2, we * uv.z);
  unsafeAtomicAdd(id + 3, we * uv.w);
}

__global__ __launch_bounds__(256) void add_scale_kernel(
    float* __restrict__ acc, const float* __restrict__ add, float s, long long n4) {
  long long i = (long long)blockIdx.x * blockDim.x + threadIdx.x;
  if (i >= n4) return;
  float4 a = ((const float4*)acc)[i];
  float4 b = ((const float4*)add)[i];
  a.x = (a.x + b.x) * s;
  a.y = (a.y + b.y) * s;
  a.z = (a.z + b.z) * s;
  a.w = (a.w + b.w) * s;
  ((float4*)acc)[i] = a;
}

extern "C" void kernel_launch(void* const* d_in, const int* in_sizes, int n_in,
                              void* d_out, int out_size, void* d_ws, size_t ws_size,
                              hipStream_t stream) {
  const float* user_emb = (const float*)d_in[1];
  const float* item_emb = (const float*)d_in[2];
  const int*   edges    = (const int*)d_in[3];
  const int*   u_idx    = edges;            // row 0
  const int*   i_idx    = edges + N_EDGES;  // row 1
  const float* w        = (const float*)d_in[4];

  float* out = (float*)d_out;  // [item_acc | user_acc]

  // workspace layout (4B units)
  float* buf_a   = (float*)d_ws;                 // TOT_ELEMS
  float* buf_b   = buf_a + TOT_ELEMS;            // TOT_ELEMS
  int2*  csr     = (int2*)(buf_b + TOT_ELEMS);   // NDIR int2
  int*   counts  = (int*)(csr + NDIR);           // NROWS
  int*   row_ptr = counts + NROWS;               // NROWS + 1
  int*   cursor  = row_ptr + NROWS + 1;          // NROWS
  int*   blksums = cursor + NROWS;               // 1024
  const size_t needed =
      ((size_t)2 * TOT_ELEMS + 2 * (size_t)NDIR + 3 * (size_t)NROWS + 1 + 1024) * 4;

  if (ws_size >= needed) {
    // ---- CSR build (once per call) ----
    hipMemsetAsync(counts, 0, (size_t)NROWS * sizeof(int), stream);
    const int qblocks = (QEDGES + 255) / 256;  // 1954
    hist_kernel<<<qblocks, 256, 0, stream>>>(u_idx, i_idx, counts);
    const int nblocksA = (NROWS + 255) / 256;  // 587 <= 1024
    scanA_kernel<<<nblocksA, 256, 0, stream>>>(counts, row_ptr, blksums, NROWS);
    scanB_kernel<<<1, 1024, 0, stream>>>(blksums, nblocksA);
    scanC_kernel<<<nblocksA, 256, 0, stream>>>(row_ptr, blksums, cursor, NROWS);
    scatter_csr_win<<<PASSES * BPP, 256, 0, stream>>>(
        u_idx, i_idx, w, cursor, csr);

    // ---- layers (gather + fused residual) ----
    const int gather_blocks = (NROWS + 3) / 4;  // 4 rows (waves) per block
    // L1: gather from input tables; out = emb + l1; buf_a = l1
    gather_fused<0><<<gather_blocks, 256, 0, stream>>>(
        item_emb, user_emb, buf_a, out, csr, row_ptr);
    // L2: gather from buf_a; out += l2; buf_b = l2
    gather_fused<1><<<gather_blocks, 256, 0, stream>>>(
        buf_a, buf_a + ITEM_ELEMS, buf_b, out, csr, row_ptr);
    // L3: gather from buf_b; out = (out + l3) * 0.25
    gather_fused<2><<<gather_blocks, 256, 0, stream>>>(
        buf_b, buf_b + ITEM_ELEMS, nullptr, out, csr, row_ptr);
  } else {
    // ---- fallback: R1 atomic scatter ----
    const size_t item_bytes = (size_t)ITEM_ELEMS * sizeof(float);
    const size_t user_bytes = (size_t)USER_ELEMS * sizeof(float);
    hipMemcpyAsync(buf_a,              item_emb, item_bytes, hipMemcpyDeviceToDevice, stream);
    hipMemcpyAsync(buf_a + ITEM_ELEMS, user_emb, user_bytes, hipMemcpyDeviceToDevice, stream);
    hipMemcpyAsync(out,                item_emb, item_bytes, hipMemcpyDeviceToDevice, stream);
    hipMemcpyAsync(out + ITEM_ELEMS,   user_emb, user_bytes, hipMemcpyDeviceToDevice, stream);
    const long long st = (long long)N_EDGES * 16;
    const int sb = (int)((st + 255) / 256);
    const long long n4 = TOT_ELEMS / 4;
    const int add_blocks = (int)((n4 + 255) / 256);
    float* src = buf_a;
    float* dst = buf_b;
    for (int l = 0; l < LAYERS; ++l) {
      hipMemsetAsync(dst, 0, (size_t)TOT_ELEMS * sizeof(float), stream);
      atomic_scatter_kernel<<<sb, 256, 0, stream>>>(src, dst, u_idx, i_idx, w);
      const float s = (l == LAYERS - 1) ? (1.0f / (LAYERS + 1)) : 1.0f;
      add_scale_kernel<<<add_blocks, 256, 0, stream>>>(out, dst, s, n4);
      float* t = src; src = dst; dst = t;
    }
  }
}